// Round 7
// baseline (197.128 us; speedup 1.0000x reference)
//
#include <hip/hip_runtime.h>
#include <stdint.h>

// YOLO loss R7: R6 (persistent 1-wave blocks, NT loads, no barriers) with
// LDS halved: only pred goes through the LDS transpose (7680 B/block ->
// 16 blocks/CU, GRID 4096); target is loaded per-lane directly with
// unaligned-dword NT dwordx4 loads, register double-buffered one tile ahead
// (manual ping-pong, 2x-unrolled loop -> no dynamic reg indexing).

#define NCLS 20
#define SLOTS 128
#define GRID 4096            // 16 blocks/CU * 256 CUs
#define TILES 12544          // 802816 cells / 64 cells per tile

typedef float f4 __attribute__((ext_vector_type(4), aligned(4)));

__device__ static inline f4 ldg4nt(const float* p) {
    return __builtin_nontemporal_load((const f4*)p);
}

__global__ __launch_bounds__(64) void yolo_main(
    const float* __restrict__ pred,
    const float* __restrict__ target,
    float* __restrict__ ws)
{
    __shared__ float sp[64 * 30];  // 7680 B — pred transpose only

    const int lane = threadIdx.x;
    const int blk  = blockIdx.x;
    const int n = (TILES - blk + GRID - 1) / GRID;   // 3 or 4 tiles

    const float EPS = 1e-6f;

    f4 rp0, rp1, rp2, rp3, rp4, rp5, rp6, rp7;       // pred staging regs

    // target ping-pong sets: 5 class f4 + 1 box f4 + 1 scalar each
    f4 ta0, ta1, ta2, ta3, ta4, ta5;  float tas;
    f4 tb0, tb1, tb2, tb3, tb4, tb5;  float tbs;

#define LOAD_P(TILE) do {                                              \
        const float* gp = pred + (size_t)(TILE) * 1920;                \
        rp0 = ldg4nt(gp + lane * 4 + 0 * 256);                         \
        rp1 = ldg4nt(gp + lane * 4 + 1 * 256);                         \
        rp2 = ldg4nt(gp + lane * 4 + 2 * 256);                         \
        rp3 = ldg4nt(gp + lane * 4 + 3 * 256);                         \
        rp4 = ldg4nt(gp + lane * 4 + 4 * 256);                         \
        rp5 = ldg4nt(gp + lane * 4 + 5 * 256);                         \
        rp6 = ldg4nt(gp + lane * 4 + 6 * 256);                         \
        if (lane < 32) rp7 = ldg4nt(gp + lane * 4 + 7 * 256);          \
    } while (0)

#define DUMP_P() do {                                                  \
        *(f4*)(sp + lane * 4 + 0 * 256) = rp0;                         \
        *(f4*)(sp + lane * 4 + 1 * 256) = rp1;                         \
        *(f4*)(sp + lane * 4 + 2 * 256) = rp2;                         \
        *(f4*)(sp + lane * 4 + 3 * 256) = rp3;                         \
        *(f4*)(sp + lane * 4 + 4 * 256) = rp4;                         \
        *(f4*)(sp + lane * 4 + 5 * 256) = rp5;                         \
        *(f4*)(sp + lane * 4 + 6 * 256) = rp6;                         \
        if (lane < 32) *(f4*)(sp + lane * 4 + 7 * 256) = rp7;          \
    } while (0)

#define LOAD_T(S0,S1,S2,S3,S4,S5,SS,TILE) do {                         \
        const float* gt = target + (size_t)(TILE) * 1600 + lane * 25;  \
        S0 = ldg4nt(gt + 0);  S1 = ldg4nt(gt + 4);                     \
        S2 = ldg4nt(gt + 8);  S3 = ldg4nt(gt + 12);                    \
        S4 = ldg4nt(gt + 16); S5 = ldg4nt(gt + 20);                    \
        SS = __builtin_nontemporal_load(gt + 24);                      \
    } while (0)

    // compute one cell: pred from LDS (lp), target from regs
    auto cell = [&](const float* lp, f4 c0, f4 c1, f4 c2, f4 c3, f4 c4,
                    f4 b5, float th) -> float {
        const float tobj = b5.x;
        const float tx = b5.y, ty = b5.z, tw = b5.w;

        const float t_x1 = tx - tw * 0.5f, t_x2 = tx + tw * 0.5f;
        const float t_y1 = ty - th * 0.5f, t_y2 = ty + th * 0.5f;
        const float t_area = fabsf((t_x2 - t_x1) * (t_y2 - t_y1));

        float iou[2];
        #pragma unroll
        for (int b = 0; b < 2; ++b) {
            const float bx = lp[NCLS + 5 * b + 1];
            const float by = lp[NCLS + 5 * b + 2];
            const float bw = lp[NCLS + 5 * b + 3];
            const float bh = lp[NCLS + 5 * b + 4];
            const float x1 = bx - bw * 0.5f, x2 = bx + bw * 0.5f;
            const float y1 = by - bh * 0.5f, y2 = by + bh * 0.5f;
            const float iw = fmaxf(fminf(x2, t_x2) - fmaxf(x1, t_x1), 0.0f);
            const float ih = fmaxf(fminf(y2, t_y2) - fmaxf(y1, t_y1), 0.0f);
            const float inter = iw * ih;
            const float a1 = fabsf((x2 - x1) * (y2 - y1));
            iou[b] = inter / (a1 + t_area - inter + EPS);
        }
        const int best = (iou[1] > iou[0]) ? 1 : 0;

        const float bconf = lp[NCLS + 5 * best + 0];
        const float bxv   = lp[NCLS + 5 * best + 1];
        const float byv   = lp[NCLS + 5 * best + 2];
        const float bwv   = lp[NCLS + 5 * best + 3];
        const float bhv   = lp[NCLS + 5 * best + 4];

        const float sgnw = (bwv > 0.f) ? 1.f : ((bwv < 0.f) ? -1.f : 0.f);
        const float sgnh = (bhv > 0.f) ? 1.f : ((bhv < 0.f) ? -1.f : 0.f);
        const float swv = sgnw * sqrtf(fabsf(bwv) + EPS);
        const float shv = sgnh * sqrtf(fabsf(bhv) + EPS);

        float d0 = tobj * bxv - tobj * tx;
        float d1 = tobj * byv - tobj * ty;
        float d2 = tobj * swv - sqrtf(fmaxf(tobj * tw, 0.0f));
        float d3 = tobj * shv - sqrtf(fmaxf(tobj * th, 0.0f));
        float box_loss = d0 * d0 + d1 * d1 + d2 * d2 + d3 * d3;

        const float noobj = 1.0f - tobj;
        float n0 = noobj * (lp[NCLS + 0] - tobj);
        float n1 = noobj * (lp[NCLS + 5] - tobj);
        float no_object_loss = n0 * n0 + n1 * n1;

        float od = tobj * (bconf - tobj);
        float object_loss = od * od;

        const f4 tc[5] = {c0, c1, c2, c3, c4};
        float class_loss = 0.0f;
        #pragma unroll
        for (int v = 0; v < 5; ++v) {
            #pragma unroll
            for (int k = 0; k < 4; ++k) {
                float cd = tobj * (lp[v * 4 + k] - tc[v][k]);
                class_loss += cd * cd;
            }
        }

        return 5.0f * box_loss + object_loss + 0.5f * no_object_loss + class_loss;
    };

    // ---- prologue: tile 0 into pred regs + target set A
    LOAD_P(blk);
    LOAD_T(ta0, ta1, ta2, ta3, ta4, ta5, tas, blk);

    float acc = 0.0f;
    int i = 0;
    while (i < n) {
        // ---- tile i (set A)
        DUMP_P();                                    // waits pred(i) vmcnt
        if (i + 1 < n) {
            LOAD_P(blk + (i + 1) * GRID);
            LOAD_T(tb0, tb1, tb2, tb3, tb4, tb5, tbs, blk + (i + 1) * GRID);
        }
        acc += cell(sp + lane * 30, ta0, ta1, ta2, ta3, ta4, ta5, tas);
        __asm__ volatile("" ::: "memory");
        ++i;
        if (i >= n) break;

        // ---- tile i (set B)
        DUMP_P();
        if (i + 1 < n) {
            LOAD_P(blk + (i + 1) * GRID);
            LOAD_T(ta0, ta1, ta2, ta3, ta4, ta5, tas, blk + (i + 1) * GRID);
        }
        acc += cell(sp + lane * 30, tb0, tb1, tb2, tb3, tb4, tb5, tbs);
        __asm__ volatile("" ::: "memory");
        ++i;
    }

    // wave reduce + one spread atomic per wave
    #pragma unroll
    for (int off = 32; off > 0; off >>= 1)
        acc += __shfl_down(acc, off, 64);

    if (lane == 0)
        atomicAdd(&ws[blk & (SLOTS - 1)], acc);
}

__global__ __launch_bounds__(64) void yolo_reduce(
    const float* __restrict__ ws, float* __restrict__ out)
{
    const int lane = threadIdx.x;
    float s = ws[lane] + ws[lane + 64];
    #pragma unroll
    for (int off = 32; off > 0; off >>= 1)
        s += __shfl_down(s, off, 64);
    if (lane == 0) out[0] = s;
}

extern "C" void kernel_launch(void* const* d_in, const int* in_sizes, int n_in,
                              void* d_out, int out_size, void* d_ws, size_t ws_size,
                              hipStream_t stream) {
    const float* pred   = (const float*)d_in[0];
    const float* target = (const float*)d_in[1];
    float* ws  = (float*)d_ws;
    float* out = (float*)d_out;

    hipMemsetAsync(ws, 0, SLOTS * sizeof(float), stream);

    hipLaunchKernelGGL(yolo_main, dim3(GRID), dim3(64), 0, stream,
                       pred, target, ws);
    hipLaunchKernelGGL(yolo_reduce, dim3(1), dim3(64), 0, stream, ws, out);
}